// Round 9
// baseline (165.183 us; speedup 1.0000x reference)
//
#include <hip/hip_runtime.h>
#include <hip/hip_bf16.h>
#include <hip/hip_cooperative_groups.h>

namespace cg = cooperative_groups;

typedef __bf16 bf16;
typedef __bf16 bf16x4 __attribute__((ext_vector_type(4)));
typedef __bf16 bf16x8 __attribute__((ext_vector_type(8)));
typedef float f32x4 __attribute__((ext_vector_type(4)));

#define NEGV -9.0e15f

#define GLD16(gp, lp)                                                    \
  __builtin_amdgcn_global_load_lds(                                     \
      (const __attribute__((address_space(1))) void*)(gp),              \
      (__attribute__((address_space(3))) void*)(lp), 16, 0, 0)

// ---------------- prep: x->bf16, Wqkv^T (col-reordered), Wo^T ----------------
// Wqkv column n = h*192 + sel*64 + d  ->  n' = sel*512 + h*64 + d

__global__ __launch_bounds__(256) void k_prep(
    const float* __restrict__ x, const float* __restrict__ Wqkv, const float* __restrict__ Wo,
    bf16* __restrict__ xb, bf16* __restrict__ WqkvT, bf16* __restrict__ WoT) {
  const int bid = blockIdx.x, tid = threadIdx.x;
  if (bid < 2048) {               // x convert: 2048 * 1024 floats
    int i = bid * 1024 + tid * 4;
    float4 v = *(const float4*)(x + i);
    bf16x4 o;
    o[0] = (bf16)v.x; o[1] = (bf16)v.y; o[2] = (bf16)v.z; o[3] = (bf16)v.w;
    *(bf16x4*)(xb + i) = o;
    return;
  }
  __shared__ float tl[32][33];
  const float* src; bf16* dst; int N, t; bool remap;
  if (bid < 2816) { t = bid - 2048; src = Wqkv; dst = WqkvT; N = 1536; remap = true; }
  else            { t = bid - 2816; src = Wo;   dst = WoT;   N = 512;  remap = false; }
  const int tk = t & 15, tn = t >> 4;
  const int c = tid & 31, r0 = tid >> 5;
  for (int rr = 0; rr < 4; ++rr) {
    int row = r0 + rr * 8;
    tl[row][c] = src[(size_t)(tk * 32 + row) * N + tn * 32 + c];
  }
  __syncthreads();
  for (int rr = 0; rr < 4; ++rr) {
    int row = r0 + rr * 8;
    int nn = tn * 32 + row;
    int np = nn;
    if (remap) {
      int h = nn / 192, r2 = nn - h * 192, sel = r2 >> 6, d = r2 & 63;
      np = sel * 512 + h * 64 + d;
    }
    dst[(size_t)np * 512 + tk * 32 + c] = (bf16)tl[c][row];
  }
}

// ---------------- GEMM 1: BM=128, BN=64, 4 waves 64x32, 2-phase dbuf LDS ----------------
// Grid (32,24) = 768 = 3 blocks/CU (48KB LDS). sel: 0=Q 1=K 2=V.

__global__ __launch_bounds__(256) void k_gemm_qkv(
    const bf16* __restrict__ A, const bf16* __restrict__ BT, const float* __restrict__ bias,
    bf16* __restrict__ Qb, bf16* __restrict__ Kb, bf16* __restrict__ VTb) {
  __shared__ __align__(16) char lds[49152];  // As0@0, As1@16K, Bs0@32K, Bs1@40K
  const int m0 = blockIdx.x * 128, n0 = blockIdx.y * 64;
  const int sel = blockIdx.y >> 3;
  const bool isV = (sel == 2);
  const int tid = threadIdx.x, wave = tid >> 6, lane = tid & 63;
  const int wr = (wave >> 1) * 64, wc = (wave & 1) * 32;
  const int lr = lane & 15, lg = lane >> 4;
  const int srow = lane >> 3, scolb = (lane & 7) << 4;
  const char* Ab = (const char*)A;
  const char* Bb = (const char*)BT;
  f32x4 acc[4][2] = {};

  auto STAGE = [&](int buf, int kb) {
    char* Asb = lds + buf * 16384;
    char* Bsb = lds + 32768 + buf * 8192;
#pragma unroll
    for (int t = 0; t < 4; ++t) {
      int chunk = wave * 4 + t;
      GLD16(Ab + (size_t)(m0 + chunk * 8 + srow) * 1024 + kb + scolb, Asb + chunk * 1024);
    }
#pragma unroll
    for (int t = 0; t < 2; ++t) {
      int chunk = wave * 2 + t;
      GLD16(Bb + (size_t)(n0 + chunk * 8 + srow) * 1024 + kb + scolb, Bsb + chunk * 1024);
    }
  };

  STAGE(0, 0);
  asm volatile("s_waitcnt vmcnt(0)" ::: "memory");
  __syncthreads();

  for (int it = 0; it < 8; ++it) {
    const int cur = it & 1;
    if (it < 7) STAGE(cur ^ 1, (it + 1) * 128);
    const char* As = lds + cur * 16384;
    const char* Bs = lds + 32768 + cur * 8192;
#pragma unroll
    for (int kk = 0; kk < 2; ++kk) {
      bf16x8 af[4], bfr[2];
#pragma unroll
      for (int m = 0; m < 4; ++m)
        af[m] = *(const bf16x8*)(As + (wr + m * 16 + lr) * 128 + kk * 64 + lg * 16);
#pragma unroll
      for (int n = 0; n < 2; ++n)
        bfr[n] = *(const bf16x8*)(Bs + (wc + n * 16 + lr) * 128 + kk * 64 + lg * 16);
      if (!isV) {
#pragma unroll
        for (int m = 0; m < 4; ++m)
#pragma unroll
          for (int n = 0; n < 2; ++n)
            acc[m][n] = __builtin_amdgcn_mfma_f32_16x16x32_bf16(af[m], bfr[n], acc[m][n], 0, 0, 0);
      } else {
#pragma unroll
        for (int m = 0; m < 4; ++m)
#pragma unroll
          for (int n = 0; n < 2; ++n)
            acc[m][n] = __builtin_amdgcn_mfma_f32_16x16x32_bf16(bfr[n], af[m], acc[m][n], 0, 0, 0);
      }
    }
    if (it < 7) {
      asm volatile("s_waitcnt vmcnt(0)" ::: "memory");
      __builtin_amdgcn_s_barrier();
      asm volatile("" ::: "memory");
    }
  }

  if (!isV) {
    bf16* Dst = sel ? Kb : Qb;
    float bv[2]; int hh[2], dd[2];
#pragma unroll
    for (int n = 0; n < 2; ++n) {
      int gn = n0 + wc + n * 16 + lr;
      hh[n] = (gn >> 6) & 7; dd[n] = gn & 63;
      bv[n] = bias[hh[n] * 192 + sel * 64 + dd[n]];
    }
#pragma unroll
    for (int m = 0; m < 4; ++m)
#pragma unroll
      for (int r = 0; r < 4; ++r) {
        int gm = m0 + wr + m * 16 + lg * 4 + r;
        int b = gm >> 11, s = gm & 2047;
#pragma unroll
        for (int n = 0; n < 2; ++n) {
          float v = acc[m][n][r] + bv[n];
          Dst[((size_t)(b * 8 + hh[n]) * 2048 + s) * 64 + dd[n]] = (bf16)v;
        }
      }
  } else {
#pragma unroll
    for (int m = 0; m < 4; ++m) {
      int gm = m0 + wr + m * 16 + lr;
      int b = gm >> 11, s = gm & 2047;
#pragma unroll
      for (int n = 0; n < 2; ++n)
#pragma unroll
        for (int r = 0; r < 4; ++r) {
          int gn = n0 + wc + n * 16 + lg * 4 + r;
          int h = (gn >> 6) & 7, d = gn & 63;
          float v = acc[m][n][r] + bias[h * 192 + 128 + d];
          VTb[((size_t)(b * 8 + h) * 64 + d) * 2048 + s] = (bf16)v;
        }
    }
  }
}

// ---------------- attention body (shared by standalone + fused) ----------------
// smem layout: Ks@0 (16K), VTs@16K (16K), Ps@32K (16K), pmk@48K (512B) = 49664B

__device__ __forceinline__ void attn_body(
    int qb, int bh, const bf16* Qb, const bf16* Kb, const bf16* VTb,
    const int* pm, bf16* AO, char* smem) {
  char* Ks  = smem;
  char* VTs = smem + 16384;
  char* Ps  = smem + 32768;
  float* pmk = (float*)(smem + 49152);

  const int b = bh >> 3, h = bh & 7;
  const int q0 = qb * 64, kstart = q0 - 32;
  const int tid = threadIdx.x, wave = tid >> 6, lane = tid & 63;
  const int lr = lane & 15, lg = lane >> 4;

  const bf16* Qg = Qb + (size_t)bh * (2048 * 64);
  const bf16* Kg = Kb + (size_t)bh * (2048 * 64);
  const bf16* Vg = VTb + (size_t)bh * (64 * 2048);

  // K staging: pre-swizzled source (m173 pattern)
  const int srow8 = lane >> 3;
  const int srcsw8 = ((lane & 7) ^ (srow8 & 7)) << 4;
#pragma unroll
  for (int t = 0; t < 4; ++t) {
    int chunk = wave * 4 + t;
    int row = chunk * 8 + srow8;
    int sk = kstart + row;
    sk = sk < 0 ? 0 : (sk > 2047 ? 2047 : sk);
    GLD16((const char*)Kg + (size_t)sk * 128 + srcsw8, Ks + chunk * 1024);
  }
  // V^T staging
  {
    int srow4 = lane >> 4, cb = (lane & 15) << 4;
#pragma unroll
    for (int t = 0; t < 4; ++t) {
      int chunk = wave * 4 + t;
      int d = chunk * 4 + srow4;
      int csw = cb ^ ((d & 7) << 4);
      int sl = kstart + (csw >> 1);
      sl = sl < 0 ? 0 : (sl > 2040 ? 2040 : sl);
      GLD16((const char*)Vg + (size_t)d * 4096 + (size_t)sl * 2, VTs + chunk * 1024);
    }
  }
  // Q fragments direct from global — issued now, consumed after barrier
  const size_t qoff = (size_t)(q0 + wave * 16 + lr) * 64;
  bf16x8 qf0 = *(const bf16x8*)(Qg + qoff + lg * 8);
  bf16x8 qf1 = *(const bf16x8*)(Qg + qoff + 32 + lg * 8);

  if (tid < 128) {
    int sk = kstart + tid;
    pmk[tid] = (sk >= 0 && sk < 2048 && pm[b * 2048 + sk] != 0) ? 0.0f : NEGV;
  }
  __syncthreads();

  // scores S = Q.K^T : 16 q-rows x 128 keys per wave
  const int kxor = (lr & 7) << 4;
  f32x4 sc[8] = {};
  __builtin_amdgcn_s_setprio(1);
#pragma unroll
  for (int kk = 0; kk < 2; ++kk) {
    bf16x8 qf = kk ? qf1 : qf0;
    int colb = kk * 64 + lg * 16;
#pragma unroll
    for (int nt = 0; nt < 8; ++nt) {
      int krow = nt * 16 + lr;
      bf16x8 kf = *(const bf16x8*)(Ks + krow * 128 + (colb ^ kxor));
      sc[nt] = __builtin_amdgcn_mfma_f32_16x16x32_bf16(qf, kf, sc[nt], 0, 0, 0);
    }
  }
  __builtin_amdgcn_s_setprio(0);

  // mask + exp, no max-subtraction (validated rounds 5-8)
  float msk[8];
#pragma unroll
  for (int nt = 0; nt < 8; ++nt) msk[nt] = pmk[nt * 16 + lr];
  float rsum[4] = {0.f, 0.f, 0.f, 0.f};
#pragma unroll
  for (int nt = 0; nt < 8; ++nt) {
    int j = nt * 16 + lr;
#pragma unroll
    for (int r = 0; r < 4; ++r) {
      int qrow = wave * 16 + lg * 4 + r;
      float v = fmaf(sc[nt][r], 0.125f, msk[nt]);
      v = ((unsigned)(j - qrow) <= 64u) ? v : NEGV;
      float p = __expf(v);
      sc[nt][r] = p;
      rsum[r] += p;
    }
  }
#pragma unroll
  for (int off = 1; off < 16; off <<= 1)
#pragma unroll
    for (int r = 0; r < 4; ++r)
      rsum[r] += __shfl_xor(rsum[r], off);
#pragma unroll
  for (int r = 0; r < 4; ++r) rsum[r] = fmaxf(rsum[r], 1e-30f);

  // unnormalized P -> LDS (bf16)
#pragma unroll
  for (int nt = 0; nt < 8; ++nt)
#pragma unroll
    for (int r = 0; r < 4; ++r) {
      int qrow = wave * 16 + lg * 4 + r;
      int colb = (nt * 16 + lr) * 2;
      *(bf16*)(Ps + qrow * 256 + (colb ^ ((qrow & 7) << 4))) = (bf16)sc[nt][r];
    }
  __syncthreads();

  // O = P.V : 16 q-rows x 64 d per wave, K=128
  f32x4 oacc[4] = {};
  __builtin_amdgcn_s_setprio(1);
#pragma unroll
  for (int ks = 0; ks < 4; ++ks) {
    int colb = ks * 64 + lg * 16;
    int prow = wave * 16 + lr;
    bf16x8 pf = *(const bf16x8*)(Ps + prow * 256 + (colb ^ ((prow & 7) << 4)));
#pragma unroll
    for (int n = 0; n < 4; ++n) {
      int vrow = n * 16 + lr;
      bf16x8 vf = *(const bf16x8*)(VTs + vrow * 256 + (colb ^ ((vrow & 7) << 4)));
      oacc[n] = __builtin_amdgcn_mfma_f32_16x16x32_bf16(pf, vf, oacc[n], 0, 0, 0);
    }
  }
  __builtin_amdgcn_s_setprio(0);

  float inv[4];
#pragma unroll
  for (int r = 0; r < 4; ++r) inv[r] = 1.0f / rsum[r];
#pragma unroll
  for (int r = 0; r < 4; ++r) {
    int qrow = wave * 16 + lg * 4 + r;
    float s2 = (pmk[32 + qrow] == 0.0f) ? inv[r] : 0.0f;
#pragma unroll
    for (int n = 0; n < 4; ++n)
      AO[(size_t)(b * 2048 + q0 + qrow) * 512 + h * 64 + n * 16 + lr] = (bf16)(oacc[n][r] * s2);
  }
}

// ---------------- GEMM2 body: 64x64 tile, 4 waves 32x32, 2-phase dbuf ----------------
// smem: A0@0, A1@8K, B0@16K, B1@24K (32KB)

__device__ __forceinline__ void gemm2_body(
    int m0, int n0, const bf16* A, const bf16* BT, const float* bias, float* C, char* lds) {
  const int tid = threadIdx.x, wave = tid >> 6, lane = tid & 63;
  const int wr = (wave >> 1) * 32, wc = (wave & 1) * 32;
  const int lr = lane & 15, lg = lane >> 4;
  const int srow = lane >> 3, scolb = (lane & 7) << 4;
  const char* Ab = (const char*)A;
  const char* Bb = (const char*)BT;
  f32x4 acc[2][2] = {};

  auto STAGE = [&](int buf, int kb) {
    char* Asb = lds + buf * 8192;
    char* Bsb = lds + 16384 + buf * 8192;
#pragma unroll
    for (int t = 0; t < 2; ++t) {
      int chunk = wave * 2 + t;
      GLD16(Ab + (size_t)(m0 + chunk * 8 + srow) * 1024 + kb + scolb, Asb + chunk * 1024);
      GLD16(Bb + (size_t)(n0 + chunk * 8 + srow) * 1024 + kb + scolb, Bsb + chunk * 1024);
    }
  };

  STAGE(0, 0);
  asm volatile("s_waitcnt vmcnt(0)" ::: "memory");
  __syncthreads();

  for (int it = 0; it < 8; ++it) {
    const int cur = it & 1;
    if (it < 7) STAGE(cur ^ 1, (it + 1) * 128);
    const char* As = lds + cur * 8192;
    const char* Bs = lds + 16384 + cur * 8192;
#pragma unroll
    for (int kk = 0; kk < 2; ++kk) {
      bf16x8 af[2], bfr[2];
#pragma unroll
      for (int m = 0; m < 2; ++m)
        af[m] = *(const bf16x8*)(As + (wr + m * 16 + lr) * 128 + kk * 64 + lg * 16);
#pragma unroll
      for (int n = 0; n < 2; ++n)
        bfr[n] = *(const bf16x8*)(Bs + (wc + n * 16 + lr) * 128 + kk * 64 + lg * 16);
#pragma unroll
      for (int m = 0; m < 2; ++m)
#pragma unroll
        for (int n = 0; n < 2; ++n)
          acc[m][n] = __builtin_amdgcn_mfma_f32_16x16x32_bf16(af[m], bfr[n], acc[m][n], 0, 0, 0);
    }
    if (it < 7) {
      asm volatile("s_waitcnt vmcnt(0)" ::: "memory");
      __builtin_amdgcn_s_barrier();
      asm volatile("" ::: "memory");
    }
  }

  float bv0 = bias[n0 + wc + lr], bv1 = bias[n0 + wc + 16 + lr];
#pragma unroll
  for (int m = 0; m < 2; ++m)
#pragma unroll
    for (int n = 0; n < 2; ++n)
#pragma unroll
      for (int r = 0; r < 4; ++r) {
        int gm = m0 + wr + m * 16 + lg * 4 + r;
        int gn = n0 + wc + n * 16 + lr;
        C[(size_t)gm * 512 + gn] = acc[m][n][r] + (n ? bv1 : bv0);
      }
}

// ---------------- fused attn + GEMM2 (cooperative, grid 512 x 256) ----------------

__global__ __launch_bounds__(256) void k_attn_out(
    const bf16* Qb, const bf16* Kb, const bf16* VTb, const int* pm, bf16* AO,
    const bf16* WoT, const float* bo, float* C) {
  __shared__ __align__(16) char smem[49664];
  const int bid = blockIdx.x;
  attn_body(bid & 31, bid >> 5, Qb, Kb, VTb, pm, AO, smem);
  __threadfence();                       // device-scope: AO visible cross-XCD
  cg::this_grid().sync();
  gemm2_body((bid >> 3) * 64, (bid & 7) * 64, AO, WoT, bo, C, smem);
}

// ---------------- standalone fallbacks ----------------

__global__ __launch_bounds__(256) void k_attn(
    const bf16* Qb, const bf16* Kb, const bf16* VTb, const int* pm, bf16* AO) {
  __shared__ __align__(16) char smem[49664];
  attn_body(blockIdx.x, blockIdx.y, Qb, Kb, VTb, pm, AO, smem);
}

__global__ __launch_bounds__(256) void k_gemm_out64(
    const bf16* A, const bf16* BT, const float* bias, float* C) {
  __shared__ __align__(16) char lds[32768];
  gemm2_body(blockIdx.x * 64, blockIdx.y * 64, A, BT, bias, C, lds);
}

// ---------------- launch ----------------

extern "C" void kernel_launch(void* const* d_in, const int* in_sizes, int n_in,
                              void* d_out, int out_size, void* d_ws, size_t ws_size,
                              hipStream_t stream) {
  const float* x     = (const float*)d_in[0];
  const int*   pmask = (const int*)d_in[1];
  const float* Wqkv  = (const float*)d_in[2];
  const float* bqkv  = (const float*)d_in[3];
  const float* Wo    = (const float*)d_in[4];
  const float* bo    = (const float*)d_in[5];
  float* out = (float*)d_out;

  char* ws = (char*)d_ws;
  bf16* xb    = (bf16*)(ws);                 // 4 MiB
  bf16* WqkvT = (bf16*)(ws + 4194304);       // 1.5 MiB (reordered)
  bf16* WoT   = (bf16*)(ws + 5767168);       // 0.5 MiB
  bf16* Qb    = (bf16*)(ws + 6291456);       // [b][h][s][d] 4 MiB
  bf16* Kb    = (bf16*)(ws + 10485760);      // [b][h][s][d] 4 MiB
  bf16* VTb   = (bf16*)(ws + 14680064);      // [b][h][d][s] 4 MiB
  bf16* AO    = (bf16*)(ws + 18874368);      // [b][s][h*d]  4 MiB

  k_prep<<<3072, 256, 0, stream>>>(x, Wqkv, Wo, xb, WqkvT, WoT);

  dim3 g1(32, 24);
  k_gemm_qkv<<<g1, 256, 0, stream>>>(xb, WqkvT, bqkv, Qb, Kb, VTb);

  // fused attn + GEMM2 via cooperative launch (one boundary removed)
  const bf16* Qb_c = Qb; const bf16* Kb_c = Kb; const bf16* VTb_c = VTb;
  bf16* AO_c = AO; const bf16* WoT_c = WoT;
  void* kargs[] = {(void*)&Qb_c, (void*)&Kb_c, (void*)&VTb_c, (void*)&pmask,
                   (void*)&AO_c, (void*)&WoT_c, (void*)&bo, (void*)&out};
  hipError_t ce = hipLaunchCooperativeKernel((const void*)k_attn_out,
                                             dim3(512), dim3(256), kargs, 0, stream);
  if (ce != hipSuccess) {
    (void)hipGetLastError();   // clear error state; fall back to split launches
    dim3 ga(32, 16);
    k_attn<<<ga, 256, 0, stream>>>(Qb, Kb, VTb, pmask, AO);
    dim3 g2(64, 8);
    k_gemm_out64<<<g2, 256, 0, stream>>>(AO, WoT, bo, out);
  }
}

// Round 10
// 39.209 us; speedup vs baseline: 4.2128x; 4.2128x over previous
//
#include <hip/hip_runtime.h>
#include <hip/hip_bf16.h>

typedef __bf16 bf16;
typedef __bf16 bf16x4 __attribute__((ext_vector_type(4)));
typedef __bf16 bf16x8 __attribute__((ext_vector_type(8)));
typedef float f32x4 __attribute__((ext_vector_type(4)));

#define NEGV -9.0e15f

#define GLD16(gp, lp)                                                    \
  __builtin_amdgcn_global_load_lds(                                     \
      (const __attribute__((address_space(1))) void*)(gp),              \
      (__attribute__((address_space(3))) void*)(lp), 16, 0, 0)

// ---------------- prep: x->bf16, Wqkv^T (col-reordered), Wo^T ----------------
// Wqkv column n = h*192 + sel*64 + d  ->  n' = sel*512 + h*64 + d

__global__ __launch_bounds__(256) void k_prep(
    const float* __restrict__ x, const float* __restrict__ Wqkv, const float* __restrict__ Wo,
    bf16* __restrict__ xb, bf16* __restrict__ WqkvT, bf16* __restrict__ WoT) {
  const int bid = blockIdx.x, tid = threadIdx.x;
  if (bid < 2048) {               // x convert: 2048 * 1024 floats
    int i = bid * 1024 + tid * 4;
    float4 v = *(const float4*)(x + i);
    bf16x4 o;
    o[0] = (bf16)v.x; o[1] = (bf16)v.y; o[2] = (bf16)v.z; o[3] = (bf16)v.w;
    *(bf16x4*)(xb + i) = o;
    return;
  }
  __shared__ float tl[32][33];
  const float* src; bf16* dst; int N, t; bool remap;
  if (bid < 2816) { t = bid - 2048; src = Wqkv; dst = WqkvT; N = 1536; remap = true; }
  else            { t = bid - 2816; src = Wo;   dst = WoT;   N = 512;  remap = false; }
  const int tk = t & 15, tn = t >> 4;
  const int c = tid & 31, r0 = tid >> 5;
  for (int rr = 0; rr < 4; ++rr) {
    int row = r0 + rr * 8;
    tl[row][c] = src[(size_t)(tk * 32 + row) * N + tn * 32 + c];
  }
  __syncthreads();
  for (int rr = 0; rr < 4; ++rr) {
    int row = r0 + rr * 8;
    int nn = tn * 32 + row;
    int np = nn;
    if (remap) {
      int h = nn / 192, r2 = nn - h * 192, sel = r2 >> 6, d = r2 & 63;
      np = sel * 512 + h * 64 + d;
    }
    dst[(size_t)np * 512 + tk * 32 + c] = (bf16)tl[c][row];
  }
}

// ---------------- GEMM 1: BM=128, BN=64, 4 waves 64x32, 2-phase dbuf LDS ----------------
// Grid (32,24) = 768 = 3 blocks/CU (48KB LDS). sel: 0=Q 1=K 2=V.

__global__ __launch_bounds__(256) void k_gemm_qkv(
    const bf16* __restrict__ A, const bf16* __restrict__ BT, const float* __restrict__ bias,
    bf16* __restrict__ Qb, bf16* __restrict__ Kb, bf16* __restrict__ VTb) {
  __shared__ __align__(16) char lds[49152];  // As0@0, As1@16K, Bs0@32K, Bs1@40K
  const int m0 = blockIdx.x * 128, n0 = blockIdx.y * 64;
  const int sel = blockIdx.y >> 3;
  const bool isV = (sel == 2);
  const int tid = threadIdx.x, wave = tid >> 6, lane = tid & 63;
  const int wr = (wave >> 1) * 64, wc = (wave & 1) * 32;
  const int lr = lane & 15, lg = lane >> 4;
  const int srow = lane >> 3, scolb = (lane & 7) << 4;
  const char* Ab = (const char*)A;
  const char* Bb = (const char*)BT;
  f32x4 acc[4][2] = {};

  auto STAGE = [&](int buf, int kb) {
    char* Asb = lds + buf * 16384;
    char* Bsb = lds + 32768 + buf * 8192;
#pragma unroll
    for (int t = 0; t < 4; ++t) {
      int chunk = wave * 4 + t;
      GLD16(Ab + (size_t)(m0 + chunk * 8 + srow) * 1024 + kb + scolb, Asb + chunk * 1024);
    }
#pragma unroll
    for (int t = 0; t < 2; ++t) {
      int chunk = wave * 2 + t;
      GLD16(Bb + (size_t)(n0 + chunk * 8 + srow) * 1024 + kb + scolb, Bsb + chunk * 1024);
    }
  };

  STAGE(0, 0);
  asm volatile("s_waitcnt vmcnt(0)" ::: "memory");
  __syncthreads();

  for (int it = 0; it < 8; ++it) {
    const int cur = it & 1;
    if (it < 7) STAGE(cur ^ 1, (it + 1) * 128);
    const char* As = lds + cur * 16384;
    const char* Bs = lds + 32768 + cur * 8192;
#pragma unroll
    for (int kk = 0; kk < 2; ++kk) {
      bf16x8 af[4], bfr[2];
#pragma unroll
      for (int m = 0; m < 4; ++m)
        af[m] = *(const bf16x8*)(As + (wr + m * 16 + lr) * 128 + kk * 64 + lg * 16);
#pragma unroll
      for (int n = 0; n < 2; ++n)
        bfr[n] = *(const bf16x8*)(Bs + (wc + n * 16 + lr) * 128 + kk * 64 + lg * 16);
      if (!isV) {
#pragma unroll
        for (int m = 0; m < 4; ++m)
#pragma unroll
          for (int n = 0; n < 2; ++n)
            acc[m][n] = __builtin_amdgcn_mfma_f32_16x16x32_bf16(af[m], bfr[n], acc[m][n], 0, 0, 0);
      } else {
#pragma unroll
        for (int m = 0; m < 4; ++m)
#pragma unroll
          for (int n = 0; n < 2; ++n)
            acc[m][n] = __builtin_amdgcn_mfma_f32_16x16x32_bf16(bfr[n], af[m], acc[m][n], 0, 0, 0);
      }
    }
    if (it < 7) {
      asm volatile("s_waitcnt vmcnt(0)" ::: "memory");
      __builtin_amdgcn_s_barrier();
      asm volatile("" ::: "memory");
    }
  }

  if (!isV) {
    bf16* Dst = sel ? Kb : Qb;
    float bv[2]; int hh[2], dd[2];
#pragma unroll
    for (int n = 0; n < 2; ++n) {
      int gn = n0 + wc + n * 16 + lr;
      hh[n] = (gn >> 6) & 7; dd[n] = gn & 63;
      bv[n] = bias[hh[n] * 192 + sel * 64 + dd[n]];
    }
#pragma unroll
    for (int m = 0; m < 4; ++m)
#pragma unroll
      for (int r = 0; r < 4; ++r) {
        int gm = m0 + wr + m * 16 + lg * 4 + r;
        int b = gm >> 11, s = gm & 2047;
#pragma unroll
        for (int n = 0; n < 2; ++n) {
          float v = acc[m][n][r] + bv[n];
          Dst[((size_t)(b * 8 + hh[n]) * 2048 + s) * 64 + dd[n]] = (bf16)v;
        }
      }
  } else {
#pragma unroll
    for (int m = 0; m < 4; ++m) {
      int gm = m0 + wr + m * 16 + lr;
      int b = gm >> 11, s = gm & 2047;
#pragma unroll
      for (int n = 0; n < 2; ++n)
#pragma unroll
        for (int r = 0; r < 4; ++r) {
          int gn = n0 + wc + n * 16 + lg * 4 + r;
          int h = (gn >> 6) & 7, d = gn & 63;
          float v = acc[m][n][r] + bias[h * 192 + 128 + d];
          VTb[((size_t)(b * 8 + h) * 64 + d) * 2048 + s] = (bf16)v;
        }
    }
  }
}

// ---------------- attention ----------------
// grid (32, 16), 256 threads (4 waves). GLD16 K/V staging, Q direct from
// global, no max-sub softmax, setprio on MFMA clusters.
// Ps stride 272B (17x16B): G4 pad fix for the P-store 4-way bank conflict
// (1.74M SQ_LDS_BANK_CONFLICT measured in round 9's fused dispatch).

__global__ __launch_bounds__(256) void k_attn(
    const bf16* __restrict__ Qb, const bf16* __restrict__ Kb, const bf16* __restrict__ VTb,
    const int* __restrict__ pmask, bf16* __restrict__ AO) {
  __shared__ __align__(16) char Ks[128 * 128];   // [128 keys][64 d] swizzled
  __shared__ __align__(16) char VTs[64 * 256];   // [64 d][128 s] swizzled
  __shared__ __align__(16) char Ps[64 * 272];    // [64 q][128 p], stride 272 (padded)
  __shared__ float pmk[128];   // 0 = valid key, NEGV = masked

  const int qb = blockIdx.x, bh = blockIdx.y;
  const int b = bh >> 3, h = bh & 7;
  const int q0 = qb * 64, kstart = q0 - 32;
  const int tid = threadIdx.x, wave = tid >> 6, lane = tid & 63;
  const int lr = lane & 15, lg = lane >> 4;

  const bf16* Qg = Qb + (size_t)bh * (2048 * 64);
  const bf16* Kg = Kb + (size_t)bh * (2048 * 64);
  const bf16* Vg = VTb + (size_t)bh * (64 * 2048);

  // K staging: pre-swizzled source (m173 pattern)
  const int srow8 = lane >> 3;
  const int srcsw8 = ((lane & 7) ^ (srow8 & 7)) << 4;
#pragma unroll
  for (int t = 0; t < 4; ++t) {
    int chunk = wave * 4 + t;
    int row = chunk * 8 + srow8;
    int sk = kstart + row;
    sk = sk < 0 ? 0 : (sk > 2047 ? 2047 : sk);
    GLD16((const char*)Kg + (size_t)sk * 128 + srcsw8, Ks + chunk * 1024);
  }
  // V^T staging
  {
    int srow4 = lane >> 4, cb = (lane & 15) << 4;
#pragma unroll
    for (int t = 0; t < 4; ++t) {
      int chunk = wave * 4 + t;
      int d = chunk * 4 + srow4;
      int csw = cb ^ ((d & 7) << 4);
      int sl = kstart + (csw >> 1);
      sl = sl < 0 ? 0 : (sl > 2040 ? 2040 : sl);
      GLD16((const char*)Vg + (size_t)d * 4096 + (size_t)sl * 2, VTs + chunk * 1024);
    }
  }
  // Q fragments direct from global — issued now, consumed after barrier
  const size_t qoff = (size_t)(q0 + wave * 16 + lr) * 64;
  bf16x8 qf0 = *(const bf16x8*)(Qg + qoff + lg * 8);
  bf16x8 qf1 = *(const bf16x8*)(Qg + qoff + 32 + lg * 8);

  if (tid < 128) {
    int sk = kstart + tid;
    pmk[tid] = (sk >= 0 && sk < 2048 && pmask[b * 2048 + sk] != 0) ? 0.0f : NEGV;
  }
  __syncthreads();

  // scores S = Q.K^T : 16 q-rows x 128 keys per wave
  const int kxor = (lr & 7) << 4;
  f32x4 sc[8] = {};
  __builtin_amdgcn_s_setprio(1);
#pragma unroll
  for (int kk = 0; kk < 2; ++kk) {
    bf16x8 qf = kk ? qf1 : qf0;
    int colb = kk * 64 + lg * 16;
#pragma unroll
    for (int nt = 0; nt < 8; ++nt) {
      int krow = nt * 16 + lr;
      bf16x8 kf = *(const bf16x8*)(Ks + krow * 128 + (colb ^ kxor));
      sc[nt] = __builtin_amdgcn_mfma_f32_16x16x32_bf16(qf, kf, sc[nt], 0, 0, 0);
    }
  }
  __builtin_amdgcn_s_setprio(0);

  // mask + exp, no max-subtraction (validated rounds 5-8)
  float msk[8];
#pragma unroll
  for (int nt = 0; nt < 8; ++nt) msk[nt] = pmk[nt * 16 + lr];
  float rsum[4] = {0.f, 0.f, 0.f, 0.f};
#pragma unroll
  for (int nt = 0; nt < 8; ++nt) {
    int j = nt * 16 + lr;
#pragma unroll
    for (int r = 0; r < 4; ++r) {
      int qrow = wave * 16 + lg * 4 + r;
      float v = fmaf(sc[nt][r], 0.125f, msk[nt]);
      v = ((unsigned)(j - qrow) <= 64u) ? v : NEGV;
      float p = __expf(v);
      sc[nt][r] = p;
      rsum[r] += p;
    }
  }
#pragma unroll
  for (int off = 1; off < 16; off <<= 1)
#pragma unroll
    for (int r = 0; r < 4; ++r)
      rsum[r] += __shfl_xor(rsum[r], off);
#pragma unroll
  for (int r = 0; r < 4; ++r) rsum[r] = fmaxf(rsum[r], 1e-30f);

  // unnormalized P -> LDS (bf16), padded stride (no swizzle needed)
#pragma unroll
  for (int nt = 0; nt < 8; ++nt)
#pragma unroll
    for (int r = 0; r < 4; ++r) {
      int qrow = wave * 16 + lg * 4 + r;
      *(bf16*)(Ps + qrow * 272 + (nt * 16 + lr) * 2) = (bf16)sc[nt][r];
    }
  __syncthreads();

  // O = P.V : 16 q-rows x 64 d per wave, K=128
  f32x4 oacc[4] = {};
  __builtin_amdgcn_s_setprio(1);
#pragma unroll
  for (int ks = 0; ks < 4; ++ks) {
    int colb = ks * 64 + lg * 16;
    int prow = wave * 16 + lr;
    bf16x8 pf = *(const bf16x8*)(Ps + prow * 272 + colb);
#pragma unroll
    for (int n = 0; n < 4; ++n) {
      int vrow = n * 16 + lr;
      bf16x8 vf = *(const bf16x8*)(VTs + vrow * 256 + (colb ^ ((vrow & 7) << 4)));
      oacc[n] = __builtin_amdgcn_mfma_f32_16x16x32_bf16(pf, vf, oacc[n], 0, 0, 0);
    }
  }
  __builtin_amdgcn_s_setprio(0);

  float inv[4];
#pragma unroll
  for (int r = 0; r < 4; ++r) inv[r] = 1.0f / rsum[r];
#pragma unroll
  for (int r = 0; r < 4; ++r) {
    int qrow = wave * 16 + lg * 4 + r;
    float s2 = (pmk[32 + qrow] == 0.0f) ? inv[r] : 0.0f;
#pragma unroll
    for (int n = 0; n < 4; ++n)
      AO[(size_t)(b * 2048 + q0 + qrow) * 512 + h * 64 + n * 16 + lr] = (bf16)(oacc[n][r] * s2);
  }
}

// ---------------- GEMM 2: split-K 8-wave, 2-phase dbuf. out = AO @ Wo + bo ----------------
// kg = wave>>2 owns K half. LDS 96KB (still 1 block/CU at grid 256).

__global__ __launch_bounds__(512) void k_gemm_out(
    const bf16* __restrict__ A, const bf16* __restrict__ BT, const float* __restrict__ bias,
    float* __restrict__ C) {
  __shared__ __align__(16) char lds[98304];
  const int m0 = blockIdx.x * 128, n0 = blockIdx.y * 64;
  const int tid = threadIdx.x, wave = tid >> 6, lane = tid & 63;
  const int kg = wave >> 2, w2 = wave & 3;
  const int wr = (w2 >> 1) * 64, wc = (w2 & 1) * 32;
  const int lr = lane & 15, lg = lane >> 4;
  const int srow = lane >> 3, scolb = (lane & 7) << 4;
  const char* Ab = (const char*)A;
  const char* Bb = (const char*)BT;
  f32x4 acc[4][2] = {};

  auto STAGE = [&](int buf, int it) {
    char* As = lds + kg * 16384 + buf * 49152;
    char* Bs = lds + 32768 + kg * 8192 + buf * 49152;
    int kb = kg * 512 + it * 128;
#pragma unroll
    for (int t = 0; t < 4; ++t) {
      int chunk = w2 * 4 + t;
      GLD16(Ab + (size_t)(m0 + chunk * 8 + srow) * 1024 + kb + scolb, As + chunk * 1024);
    }
#pragma unroll
    for (int t = 0; t < 2; ++t) {
      int chunk = w2 * 2 + t;
      GLD16(Bb + (size_t)(n0 + chunk * 8 + srow) * 1024 + kb + scolb, Bs + chunk * 1024);
    }
  };

  STAGE(0, 0);
  asm volatile("s_waitcnt vmcnt(0)" ::: "memory");
  __syncthreads();

  for (int it = 0; it < 4; ++it) {
    const int cur = it & 1;
    if (it < 3) STAGE(cur ^ 1, it + 1);
    const char* As = lds + kg * 16384 + cur * 49152;
    const char* Bs = lds + 32768 + kg * 8192 + cur * 49152;
#pragma unroll
    for (int kk = 0; kk < 2; ++kk) {
      bf16x8 af[4], bfr[2];
#pragma unroll
      for (int m = 0; m < 4; ++m)
        af[m] = *(const bf16x8*)(As + (wr + m * 16 + lr) * 128 + kk * 64 + lg * 16);
#pragma unroll
      for (int n = 0; n < 2; ++n)
        bfr[n] = *(const bf16x8*)(Bs + (wc + n * 16 + lr) * 128 + kk * 64 + lg * 16);
#pragma unroll
      for (int m = 0; m < 4; ++m)
#pragma unroll
        for (int n = 0; n < 2; ++n)
          acc[m][n] = __builtin_amdgcn_mfma_f32_16x16x32_bf16(af[m], bfr[n], acc[m][n], 0, 0, 0);
    }
    if (it < 3) {
      asm volatile("s_waitcnt vmcnt(0)" ::: "memory");
      __builtin_amdgcn_s_barrier();
      asm volatile("" ::: "memory");
    }
  }

  // cross-group reduce: kg1 -> LDS, kg0 adds + stores
  __syncthreads();
  if (kg == 1) {
#pragma unroll
    for (int m = 0; m < 4; ++m)
#pragma unroll
      for (int n = 0; n < 2; ++n)
        *(f32x4*)(lds + (((m * 2 + n) * 256 + w2 * 64 + lane) << 4)) = acc[m][n];
  }
  __syncthreads();
  if (kg == 0) {
    float bv0 = bias[n0 + wc + lr], bv1 = bias[n0 + wc + 16 + lr];
#pragma unroll
    for (int m = 0; m < 4; ++m)
#pragma unroll
      for (int n = 0; n < 2; ++n) {
        acc[m][n] += *(const f32x4*)(lds + (((m * 2 + n) * 256 + w2 * 64 + lane) << 4));
#pragma unroll
        for (int r = 0; r < 4; ++r) {
          int gm = m0 + wr + m * 16 + lg * 4 + r;
          int gn = n0 + wc + n * 16 + lr;
          C[(size_t)gm * 512 + gn] = acc[m][n][r] + (n ? bv1 : bv0);
        }
      }
  }
}

// ---------------- launch ----------------

extern "C" void kernel_launch(void* const* d_in, const int* in_sizes, int n_in,
                              void* d_out, int out_size, void* d_ws, size_t ws_size,
                              hipStream_t stream) {
  const float* x     = (const float*)d_in[0];
  const int*   pmask = (const int*)d_in[1];
  const float* Wqkv  = (const float*)d_in[2];
  const float* bqkv  = (const float*)d_in[3];
  const float* Wo    = (const float*)d_in[4];
  const float* bo    = (const float*)d_in[5];
  float* out = (float*)d_out;

  char* ws = (char*)d_ws;
  bf16* xb    = (bf16*)(ws);                 // 4 MiB
  bf16* WqkvT = (bf16*)(ws + 4194304);       // 1.5 MiB (reordered)
  bf16* WoT   = (bf16*)(ws + 5767168);       // 0.5 MiB
  bf16* Qb    = (bf16*)(ws + 6291456);       // [b][h][s][d] 4 MiB
  bf16* Kb    = (bf16*)(ws + 10485760);      // [b][h][s][d] 4 MiB
  bf16* VTb   = (bf16*)(ws + 14680064);      // [b][h][d][s] 4 MiB
  bf16* AO    = (bf16*)(ws + 18874368);      // [b][s][h*d]  4 MiB

  k_prep<<<3072, 256, 0, stream>>>(x, Wqkv, Wo, xb, WqkvT, WoT);

  dim3 g1(32, 24);
  k_gemm_qkv<<<g1, 256, 0, stream>>>(xb, WqkvT, bqkv, Qb, Kb, VTb);

  dim3 ga(32, 16);
  k_attn<<<ga, 256, 0, stream>>>(Qb, Kb, VTb, pmask, AO);

  dim3 g2(32, 8);
  k_gemm_out<<<g2, 512, 0, stream>>>(AO, WoT, bo, out);
}

// Round 13
// 39.183 us; speedup vs baseline: 4.2157x; 1.0007x over previous
//
#include <hip/hip_runtime.h>
#include <hip/hip_bf16.h>

typedef __bf16 bf16;
typedef __bf16 bf16x4 __attribute__((ext_vector_type(4)));
typedef __bf16 bf16x8 __attribute__((ext_vector_type(8)));
typedef float f32x4 __attribute__((ext_vector_type(4)));

#define NEGV -9.0e15f

#define GLD16(gp, lp)                                                    \
  __builtin_amdgcn_global_load_lds(                                     \
      (const __attribute__((address_space(1))) void*)(gp),              \
      (__attribute__((address_space(3))) void*)(lp), 16, 0, 0)

// ---------------- prep: x->bf16, Wqkv^T (col-reordered), Wo^T ----------------
// Wqkv column n = h*192 + sel*64 + d  ->  n' = sel*512 + h*64 + d

__global__ __launch_bounds__(256) void k_prep(
    const float* __restrict__ x, const float* __restrict__ Wqkv, const float* __restrict__ Wo,
    bf16* __restrict__ xb, bf16* __restrict__ WqkvT, bf16* __restrict__ WoT) {
  const int bid = blockIdx.x, tid = threadIdx.x;
  if (bid < 2048) {               // x convert: 2048 * 1024 floats
    int i = bid * 1024 + tid * 4;
    float4 v = *(const float4*)(x + i);
    bf16x4 o;
    o[0] = (bf16)v.x; o[1] = (bf16)v.y; o[2] = (bf16)v.z; o[3] = (bf16)v.w;
    *(bf16x4*)(xb + i) = o;
    return;
  }
  __shared__ float tl[32][33];
  const float* src; bf16* dst; int N, t; bool remap;
  if (bid < 2816) { t = bid - 2048; src = Wqkv; dst = WqkvT; N = 1536; remap = true; }
  else            { t = bid - 2816; src = Wo;   dst = WoT;   N = 512;  remap = false; }
  const int tk = t & 15, tn = t >> 4;
  const int c = tid & 31, r0 = tid >> 5;
  for (int rr = 0; rr < 4; ++rr) {
    int row = r0 + rr * 8;
    tl[row][c] = src[(size_t)(tk * 32 + row) * N + tn * 32 + c];
  }
  __syncthreads();
  for (int rr = 0; rr < 4; ++rr) {
    int row = r0 + rr * 8;
    int nn = tn * 32 + row;
    int np = nn;
    if (remap) {
      int h = nn / 192, r2 = nn - h * 192, sel = r2 >> 6, d = r2 & 63;
      np = sel * 512 + h * 64 + d;
    }
    dst[(size_t)np * 512 + tk * 32 + c] = (bf16)tl[c][row];
  }
}

// ---------------- GEMM 1: BM=128, BN=64, 4 waves 64x32, 2-phase dbuf LDS ----------------
// Grid (32,24) = 768 = 3 blocks/CU (48KB LDS). sel: 0=Q 1=K 2=V.

__global__ __launch_bounds__(256) void k_gemm_qkv(
    const bf16* __restrict__ A, const bf16* __restrict__ BT, const float* __restrict__ bias,
    bf16* __restrict__ Qb, bf16* __restrict__ Kb, bf16* __restrict__ VTb) {
  __shared__ __align__(16) char lds[49152];  // As0@0, As1@16K, Bs0@32K, Bs1@40K
  const int m0 = blockIdx.x * 128, n0 = blockIdx.y * 64;
  const int sel = blockIdx.y >> 3;
  const bool isV = (sel == 2);
  const int tid = threadIdx.x, wave = tid >> 6, lane = tid & 63;
  const int wr = (wave >> 1) * 64, wc = (wave & 1) * 32;
  const int lr = lane & 15, lg = lane >> 4;
  const int srow = lane >> 3, scolb = (lane & 7) << 4;
  const char* Ab = (const char*)A;
  const char* Bb = (const char*)BT;
  f32x4 acc[4][2] = {};

  auto STAGE = [&](int buf, int kb) {
    char* Asb = lds + buf * 16384;
    char* Bsb = lds + 32768 + buf * 8192;
#pragma unroll
    for (int t = 0; t < 4; ++t) {
      int chunk = wave * 4 + t;
      GLD16(Ab + (size_t)(m0 + chunk * 8 + srow) * 1024 + kb + scolb, Asb + chunk * 1024);
    }
#pragma unroll
    for (int t = 0; t < 2; ++t) {
      int chunk = wave * 2 + t;
      GLD16(Bb + (size_t)(n0 + chunk * 8 + srow) * 1024 + kb + scolb, Bsb + chunk * 1024);
    }
  };

  STAGE(0, 0);
  asm volatile("s_waitcnt vmcnt(0)" ::: "memory");
  __syncthreads();

  for (int it = 0; it < 8; ++it) {
    const int cur = it & 1;
    if (it < 7) STAGE(cur ^ 1, (it + 1) * 128);
    const char* As = lds + cur * 16384;
    const char* Bs = lds + 32768 + cur * 8192;
#pragma unroll
    for (int kk = 0; kk < 2; ++kk) {
      bf16x8 af[4], bfr[2];
#pragma unroll
      for (int m = 0; m < 4; ++m)
        af[m] = *(const bf16x8*)(As + (wr + m * 16 + lr) * 128 + kk * 64 + lg * 16);
#pragma unroll
      for (int n = 0; n < 2; ++n)
        bfr[n] = *(const bf16x8*)(Bs + (wc + n * 16 + lr) * 128 + kk * 64 + lg * 16);
      if (!isV) {
#pragma unroll
        for (int m = 0; m < 4; ++m)
#pragma unroll
          for (int n = 0; n < 2; ++n)
            acc[m][n] = __builtin_amdgcn_mfma_f32_16x16x32_bf16(af[m], bfr[n], acc[m][n], 0, 0, 0);
      } else {
#pragma unroll
        for (int m = 0; m < 4; ++m)
#pragma unroll
          for (int n = 0; n < 2; ++n)
            acc[m][n] = __builtin_amdgcn_mfma_f32_16x16x32_bf16(bfr[n], af[m], acc[m][n], 0, 0, 0);
      }
    }
    if (it < 7) {
      asm volatile("s_waitcnt vmcnt(0)" ::: "memory");
      __builtin_amdgcn_s_barrier();
      asm volatile("" ::: "memory");
    }
  }

  if (!isV) {
    bf16* Dst = sel ? Kb : Qb;
    float bv[2]; int hh[2], dd[2];
#pragma unroll
    for (int n = 0; n < 2; ++n) {
      int gn = n0 + wc + n * 16 + lr;
      hh[n] = (gn >> 6) & 7; dd[n] = gn & 63;
      bv[n] = bias[hh[n] * 192 + sel * 64 + dd[n]];
    }
#pragma unroll
    for (int m = 0; m < 4; ++m)
#pragma unroll
      for (int r = 0; r < 4; ++r) {
        int gm = m0 + wr + m * 16 + lg * 4 + r;
        int b = gm >> 11, s = gm & 2047;
#pragma unroll
        for (int n = 0; n < 2; ++n) {
          float v = acc[m][n][r] + bv[n];
          Dst[((size_t)(b * 8 + hh[n]) * 2048 + s) * 64 + dd[n]] = (bf16)v;
        }
      }
  } else {
#pragma unroll
    for (int m = 0; m < 4; ++m) {
      int gm = m0 + wr + m * 16 + lr;
      int b = gm >> 11, s = gm & 2047;
#pragma unroll
      for (int n = 0; n < 2; ++n)
#pragma unroll
        for (int r = 0; r < 4; ++r) {
          int gn = n0 + wc + n * 16 + lg * 4 + r;
          int h = (gn >> 6) & 7, d = gn & 63;
          float v = acc[m][n][r] + bias[h * 192 + 128 + d];
          VTb[((size_t)(b * 8 + h) * 64 + d) * 2048 + s] = (bf16)v;
        }
    }
  }
}

// ---------------- attention ----------------
// grid (32, 16), 256 threads (4 waves). GLD16 K/V staging, Q direct from
// global, no max-sub softmax, setprio on MFMA clusters.
// Ps stride 272B (17x16B): G4 pad fix for the P-store 4-way bank conflict.

__global__ __launch_bounds__(256) void k_attn(
    const bf16* __restrict__ Qb, const bf16* __restrict__ Kb, const bf16* __restrict__ VTb,
    const int* __restrict__ pmask, bf16* __restrict__ AO) {
  __shared__ __align__(16) char Ks[128 * 128];   // [128 keys][64 d] swizzled
  __shared__ __align__(16) char VTs[64 * 256];   // [64 d][128 s] swizzled
  __shared__ __align__(16) char Ps[64 * 272];    // [64 q][128 p], stride 272 (padded)
  __shared__ float pmk[128];   // 0 = valid key, NEGV = masked

  const int qb = blockIdx.x, bh = blockIdx.y;
  const int b = bh >> 3, h = bh & 7;
  const int q0 = qb * 64, kstart = q0 - 32;
  const int tid = threadIdx.x, wave = tid >> 6, lane = tid & 63;
  const int lr = lane & 15, lg = lane >> 4;

  const bf16* Qg = Qb + (size_t)bh * (2048 * 64);
  const bf16* Kg = Kb + (size_t)bh * (2048 * 64);
  const bf16* Vg = VTb + (size_t)bh * (64 * 2048);

  // K staging: pre-swizzled source (m173 pattern)
  const int srow8 = lane >> 3;
  const int srcsw8 = ((lane & 7) ^ (srow8 & 7)) << 4;
#pragma unroll
  for (int t = 0; t < 4; ++t) {
    int chunk = wave * 4 + t;
    int row = chunk * 8 + srow8;
    int sk = kstart + row;
    sk = sk < 0 ? 0 : (sk > 2047 ? 2047 : sk);
    GLD16((const char*)Kg + (size_t)sk * 128 + srcsw8, Ks + chunk * 1024);
  }
  // V^T staging
  {
    int srow4 = lane >> 4, cb = (lane & 15) << 4;
#pragma unroll
    for (int t = 0; t < 4; ++t) {
      int chunk = wave * 4 + t;
      int d = chunk * 4 + srow4;
      int csw = cb ^ ((d & 7) << 4);
      int sl = kstart + (csw >> 1);
      sl = sl < 0 ? 0 : (sl > 2040 ? 2040 : sl);
      GLD16((const char*)Vg + (size_t)d * 4096 + (size_t)sl * 2, VTs + chunk * 1024);
    }
  }
  // Q fragments direct from global — issued now, consumed after barrier
  const size_t qoff = (size_t)(q0 + wave * 16 + lr) * 64;
  bf16x8 qf0 = *(const bf16x8*)(Qg + qoff + lg * 8);
  bf16x8 qf1 = *(const bf16x8*)(Qg + qoff + 32 + lg * 8);

  if (tid < 128) {
    int sk = kstart + tid;
    pmk[tid] = (sk >= 0 && sk < 2048 && pmask[b * 2048 + sk] != 0) ? 0.0f : NEGV;
  }
  __syncthreads();

  // scores S = Q.K^T : 16 q-rows x 128 keys per wave
  const int kxor = (lr & 7) << 4;
  f32x4 sc[8] = {};
  __builtin_amdgcn_s_setprio(1);
#pragma unroll
  for (int kk = 0; kk < 2; ++kk) {
    bf16x8 qf = kk ? qf1 : qf0;
    int colb = kk * 64 + lg * 16;
#pragma unroll
    for (int nt = 0; nt < 8; ++nt) {
      int krow = nt * 16 + lr;
      bf16x8 kf = *(const bf16x8*)(Ks + krow * 128 + (colb ^ kxor));
      sc[nt] = __builtin_amdgcn_mfma_f32_16x16x32_bf16(qf, kf, sc[nt], 0, 0, 0);
    }
  }
  __builtin_amdgcn_s_setprio(0);

  // mask + exp, no max-subtraction (validated rounds 5-10)
  float msk[8];
#pragma unroll
  for (int nt = 0; nt < 8; ++nt) msk[nt] = pmk[nt * 16 + lr];
  float rsum[4] = {0.f, 0.f, 0.f, 0.f};
#pragma unroll
  for (int nt = 0; nt < 8; ++nt) {
    int j = nt * 16 + lr;
#pragma unroll
    for (int r = 0; r < 4; ++r) {
      int qrow = wave * 16 + lg * 4 + r;
      float v = fmaf(sc[nt][r], 0.125f, msk[nt]);
      v = ((unsigned)(j - qrow) <= 64u) ? v : NEGV;
      float p = __expf(v);
      sc[nt][r] = p;
      rsum[r] += p;
    }
  }
#pragma unroll
  for (int off = 1; off < 16; off <<= 1)
#pragma unroll
    for (int r = 0; r < 4; ++r)
      rsum[r] += __shfl_xor(rsum[r], off);
#pragma unroll
  for (int r = 0; r < 4; ++r) rsum[r] = fmaxf(rsum[r], 1e-30f);

  // unnormalized P -> LDS (bf16), padded stride (no swizzle needed)
#pragma unroll
  for (int nt = 0; nt < 8; ++nt)
#pragma unroll
    for (int r = 0; r < 4; ++r) {
      int qrow = wave * 16 + lg * 4 + r;
      *(bf16*)(Ps + qrow * 272 + (nt * 16 + lr) * 2) = (bf16)sc[nt][r];
    }
  __syncthreads();

  // O = P.V : 16 q-rows x 64 d per wave, K=128
  f32x4 oacc[4] = {};
  __builtin_amdgcn_s_setprio(1);
#pragma unroll
  for (int ks = 0; ks < 4; ++ks) {
    int colb = ks * 64 + lg * 16;
    int prow = wave * 16 + lr;
    bf16x8 pf = *(const bf16x8*)(Ps + prow * 272 + colb);
#pragma unroll
    for (int n = 0; n < 4; ++n) {
      int vrow = n * 16 + lr;
      bf16x8 vf = *(const bf16x8*)(VTs + vrow * 256 + (colb ^ ((vrow & 7) << 4)));
      oacc[n] = __builtin_amdgcn_mfma_f32_16x16x32_bf16(pf, vf, oacc[n], 0, 0, 0);
    }
  }
  __builtin_amdgcn_s_setprio(0);

  float inv[4];
#pragma unroll
  for (int r = 0; r < 4; ++r) inv[r] = 1.0f / rsum[r];
#pragma unroll
  for (int r = 0; r < 4; ++r) {
    int qrow = wave * 16 + lg * 4 + r;
    float s2 = (pmk[32 + qrow] == 0.0f) ? inv[r] : 0.0f;
#pragma unroll
    for (int n = 0; n < 4; ++n)
      AO[(size_t)(b * 2048 + q0 + qrow) * 512 + h * 64 + n * 16 + lr] = (bf16)(oacc[n][r] * s2);
  }
}

// ---------------- GEMM 2: split-K 8-wave, 2-phase dbuf. out = AO @ Wo + bo ----------------
// kg = wave>>2 owns K half. LDS 96KB (still 1 block/CU at grid 256).

__global__ __launch_bounds__(512) void k_gemm_out(
    const bf16* __restrict__ A, const bf16* __restrict__ BT, const float* __restrict__ bias,
    float* __restrict__ C) {
  __shared__ __align__(16) char lds[98304];
  const int m0 = blockIdx.x * 128, n0 = blockIdx.y * 64;
  const int tid = threadIdx.x, wave = tid >> 6, lane = tid & 63;
  const int kg = wave >> 2, w2 = wave & 3;
  const int wr = (w2 >> 1) * 64, wc = (w2 & 1) * 32;
  const int lr = lane & 15, lg = lane >> 4;
  const int srow = lane >> 3, scolb = (lane & 7) << 4;
  const char* Ab = (const char*)A;
  const char* Bb = (const char*)BT;
  f32x4 acc[4][2] = {};

  auto STAGE = [&](int buf, int it) {
    char* As = lds + kg * 16384 + buf * 49152;
    char* Bs = lds + 32768 + kg * 8192 + buf * 49152;
    int kb = kg * 512 + it * 128;
#pragma unroll
    for (int t = 0; t < 4; ++t) {
      int chunk = w2 * 4 + t;
      GLD16(Ab + (size_t)(m0 + chunk * 8 + srow) * 1024 + kb + scolb, As + chunk * 1024);
    }
#pragma unroll
    for (int t = 0; t < 2; ++t) {
      int chunk = w2 * 2 + t;
      GLD16(Bb + (size_t)(n0 + chunk * 8 + srow) * 1024 + kb + scolb, Bs + chunk * 1024);
    }
  };

  STAGE(0, 0);
  asm volatile("s_waitcnt vmcnt(0)" ::: "memory");
  __syncthreads();

  for (int it = 0; it < 4; ++it) {
    const int cur = it & 1;
    if (it < 3) STAGE(cur ^ 1, it + 1);
    const char* As = lds + kg * 16384 + cur * 49152;
    const char* Bs = lds + 32768 + kg * 8192 + cur * 49152;
#pragma unroll
    for (int kk = 0; kk < 2; ++kk) {
      bf16x8 af[4], bfr[2];
#pragma unroll
      for (int m = 0; m < 4; ++m)
        af[m] = *(const bf16x8*)(As + (wr + m * 16 + lr) * 128 + kk * 64 + lg * 16);
#pragma unroll
      for (int n = 0; n < 2; ++n)
        bfr[n] = *(const bf16x8*)(Bs + (wc + n * 16 + lr) * 128 + kk * 64 + lg * 16);
#pragma unroll
      for (int m = 0; m < 4; ++m)
#pragma unroll
        for (int n = 0; n < 2; ++n)
          acc[m][n] = __builtin_amdgcn_mfma_f32_16x16x32_bf16(af[m], bfr[n], acc[m][n], 0, 0, 0);
    }
    if (it < 3) {
      asm volatile("s_waitcnt vmcnt(0)" ::: "memory");
      __builtin_amdgcn_s_barrier();
      asm volatile("" ::: "memory");
    }
  }

  // cross-group reduce: kg1 -> LDS, kg0 adds + stores
  __syncthreads();
  if (kg == 1) {
#pragma unroll
    for (int m = 0; m < 4; ++m)
#pragma unroll
      for (int n = 0; n < 2; ++n)
        *(f32x4*)(lds + (((m * 2 + n) * 256 + w2 * 64 + lane) << 4)) = acc[m][n];
  }
  __syncthreads();
  if (kg == 0) {
    float bv0 = bias[n0 + wc + lr], bv1 = bias[n0 + wc + 16 + lr];
#pragma unroll
    for (int m = 0; m < 4; ++m)
#pragma unroll
      for (int n = 0; n < 2; ++n) {
        acc[m][n] += *(const f32x4*)(lds + (((m * 2 + n) * 256 + w2 * 64 + lane) << 4));
#pragma unroll
        for (int r = 0; r < 4; ++r) {
          int gm = m0 + wr + m * 16 + lg * 4 + r;
          int gn = n0 + wc + n * 16 + lr;
          C[(size_t)gm * 512 + gn] = acc[m][n][r] + (n ? bv1 : bv0);
        }
      }
  }
}

// ---------------- launch ----------------

extern "C" void kernel_launch(void* const* d_in, const int* in_sizes, int n_in,
                              void* d_out, int out_size, void* d_ws, size_t ws_size,
                              hipStream_t stream) {
  const float* x     = (const float*)d_in[0];
  const int*   pmask = (const int*)d_in[1];
  const float* Wqkv  = (const float*)d_in[2];
  const float* bqkv  = (const float*)d_in[3];
  const float* Wo    = (const float*)d_in[4];
  const float* bo    = (const float*)d_in[5];
  float* out = (float*)d_out;

  char* ws = (char*)d_ws;
  bf16* xb    = (bf16*)(ws);                 // 4 MiB
  bf16* WqkvT = (bf16*)(ws + 4194304);       // 1.5 MiB (reordered)
  bf16* WoT   = (bf16*)(ws + 5767168);       // 0.5 MiB
  bf16* Qb    = (bf16*)(ws + 6291456);       // [b][h][s][d] 4 MiB
  bf16* Kb    = (bf16*)(ws + 10485760);      // [b][h][s][d] 4 MiB
  bf16* VTb   = (bf16*)(ws + 14680064);      // [b][h][d][s] 4 MiB
  bf16* AO    = (bf16*)(ws + 18874368);      // [b][s][h*d]  4 MiB

  k_prep<<<3072, 256, 0, stream>>>(x, Wqkv, Wo, xb, WqkvT, WoT);

  dim3 g1(32, 24);
  k_gemm_qkv<<<g1, 256, 0, stream>>>(xb, WqkvT, bqkv, Qb, Kb, VTb);

  dim3 ga(32, 16);
  k_attn<<<ga, 256, 0, stream>>>(Qb, Kb, VTb, pmask, AO);

  dim3 g2(32, 8);
  k_gemm_out<<<g2, 512, 0, stream>>>(AO, WoT, bo, out);
}